// Round 8
// baseline (74.303 us; speedup 1.0000x reference)
//
#include <hip/hip_runtime.h>
#include <hip/hip_fp16.h>
#include <math.h>

// B=8, C=64, H=W=64, O=128, K=3, N=9, stride=1, pad=1
// ws layout (8.61 MB; ws is ~256 MB per harness poison-fill size):
//   xTh  @ 0        : fp16 hi(x) [8][4096 pix][64 c] = 4,194,304 B
//   xTl  @ 4194304  : fp16 lo(x) [8][4096 pix][64 c] = 4,194,304 B
//   WtH  @ 8388608  : fp16 [9][128 o][64 c]          =   147,456 B
//   WtSh @ 8536064  : fp16 [9][32 ch][64 c]          =    36,864 B
//   WtSl @ 8572928  : fp16 [9][32 ch][64 c]          =    36,864 B

typedef _Float16 half8_t __attribute__((ext_vector_type(8)));
typedef float f32x4 __attribute__((ext_vector_type(4)));

// ---------------------------------------------------------------------------
// k_pre: blocks 0..511  : x (B,C,H,W) f32 -> xTh/xTl (B,HW,C) split fp16
//        blocks 512..871: conv_w -> WtH ; shift/mod weights -> WtSh/WtSl
// ---------------------------------------------------------------------------
__global__ __launch_bounds__(256) void k_pre(const float* __restrict__ x,
                                             const float* __restrict__ cw,
                                             const float* __restrict__ shift_w,
                                             const float* __restrict__ mod_w,
                                             __half* __restrict__ xTh,
                                             __half* __restrict__ xTl,
                                             __half* __restrict__ WtH,
                                             __half* __restrict__ WtSh,
                                             __half* __restrict__ WtSl) {
    __shared__ float tile[64][65];
    int bid = blockIdx.x;
    int t = threadIdx.x;
    if (bid < 512) {
        int b = bid >> 6, pt = bid & 63;
        int lane = t & 63, cq = t >> 6;
        const float* xb = x + ((size_t)b << 18);
#pragma unroll
        for (int r = 0; r < 16; ++r) {
            int c = cq * 16 + r;
            tile[c][lane] = xb[((size_t)c << 12) + pt * 64 + lane];
        }
        __syncthreads();
        int p = t >> 2, qc = t & 3;
        __align__(16) _Float16 hh[16];
        __align__(16) _Float16 ll[16];
#pragma unroll
        for (int k = 0; k < 16; ++k) {
            float v = tile[qc * 16 + k][p];
            _Float16 h = (_Float16)v;
            hh[k] = h;
            ll[k] = (_Float16)(v - (float)h);
        }
        size_t off = ((size_t)b << 18) + (size_t)(pt * 64 + p) * 64 + qc * 16;
        ((uint4*)(xTh + off))[0] = ((uint4*)hh)[0];
        ((uint4*)(xTh + off))[1] = ((uint4*)hh)[1];
        ((uint4*)(xTl + off))[0] = ((uint4*)ll)[0];
        ((uint4*)(xTl + off))[1] = ((uint4*)ll)[1];
    } else {
        int u = (bid - 512) * 256 + t;
        if (u < 73728) {
            int c = u & 63;
            int o = (u >> 6) & 127;
            int n = u >> 13;
            WtH[u] = __float2half_rn(cw[(o * 64 + c) * 9 + n]);
        } else {
            int v = u - 73728;
            if (v < 18432) {
                int c = v & 63;
                int ch = (v >> 6) & 31;
                int tap = v >> 11;
                float w = 0.f;
                if (ch < 18) w = shift_w[(ch * 64 + c) * 9 + tap];
                else if (ch < 27) w = mod_w[((ch - 18) * 64 + c) * 9 + tap];
                _Float16 h = (_Float16)w;
                _Float16 lo = (_Float16)(w - (float)h);
                WtSh[v] = *(__half*)&h;
                WtSl[v] = *(__half*)&lo;
            }
        }
    }
}

// ---------------------------------------------------------------------------
// k_fused: per block = 32 pixels (half image row) x all 128 outputs.
//   XCD swizzle: each XCD owns one batch image (x/xTh L2-resident per XCD).
//   Phase A: stage1 conv via split-fp16 MFMA; A-frags = contiguous 16B loads
//            from xTh/xTl (no strided f32 scatter).
//   Phase B: 9 x {combine -> prefetch n+1 gathers -> stage -> bar -> MFMA},
//            A double-buffered, gathers pipelined one tap ahead.
// ---------------------------------------------------------------------------
__global__ __launch_bounds__(256, 4) void k_fused(
    const __half* __restrict__ xTh, const __half* __restrict__ xTl,
    const __half* __restrict__ WtH, const __half* __restrict__ WtSh,
    const __half* __restrict__ WtSl, const float* __restrict__ shift_b,
    const float* __restrict__ mod_b, float* __restrict__ out) {
    // arena: phase A: Cred f32[64][33] @0 (8448 B)
    //        phase B: A slabs fp16[32][64] @0 and @4096 ; Ep f32[32*33] @8448
    __shared__ __align__(16) unsigned char arena[12800];
    __shared__ uint2 recU[9][32];
    __shared__ float recF[9][32];

    int t = threadIdx.x;
    int l = t & 63;
    int w = t >> 6;
    int l15 = l & 15, lhi = l >> 4;

    // XCD-aware swizzle: consecutive blockIdx round-robin XCDs; give each XCD
    // one contiguous batch image. grid 1024 = 8 * 128, bijective.
    int bid = blockIdx.x;
    int bk = (bid & 7) * 128 + (bid >> 3);
    int b = bk >> 7;
    int u = bk & 127;
    int row = u >> 1;
    int hf = u & 1;
    int col0 = hf * 32;

    const __half* xbh = xTh + ((size_t)b << 18);
    const __half* xbl = xTl + ((size_t)b << 18);

    // ---------------- Phase A: stage1 conv (MFMA, split fp16) ----------------
    {
        int wp = w >> 1;                 // pixel 16-group (0,1)
        int wh = w & 1;                  // K-half (c 0..31 / 32..63)
        int colp = col0 + wp * 16 + l15;

        f32x4 accA[2];
        accA[0] = (f32x4){0.f, 0.f, 0.f, 0.f};
        accA[1] = (f32x4){0.f, 0.f, 0.f, 0.f};
        half8_t Z;
#pragma unroll
        for (int e = 0; e < 8; ++e) Z[e] = (_Float16)0.f;

#pragma unroll
        for (int tr = 0; tr < 3; ++tr) {
            int rsh = row + tr - 1;
            if ((unsigned)rsh >= 64u) continue;    // wave-uniform border skip
#pragma unroll
            for (int tc = 0; tc < 3; ++tc) {
                int tap = tr * 3 + tc;
                int cs = colp + tc - 1;
                bool vcol = (unsigned)cs < 64u;
                size_t poff = (size_t)(rsh * 64 + (vcol ? cs : 0)) * 64 +
                              wh * 32 + (lhi << 3);
                half8_t Ah = *(const half8_t*)(xbh + poff);
                half8_t Al = *(const half8_t*)(xbl + poff);
                if (!vcol) { Ah = Z; Al = Z; }
                const __half* bh0 = WtSh + tap * 2048 + l15 * 64 + wh * 32 + (lhi << 3);
                const __half* bl0 = WtSl + tap * 2048 + l15 * 64 + wh * 32 + (lhi << 3);
#pragma unroll
                for (int nf = 0; nf < 2; ++nf) {
                    half8_t Bh = *(const half8_t*)(bh0 + nf * 1024);
                    half8_t Bl = *(const half8_t*)(bl0 + nf * 1024);
                    accA[nf] = __builtin_amdgcn_mfma_f32_16x16x32_f16(Ah, Bh, accA[nf], 0, 0, 0);
                    accA[nf] = __builtin_amdgcn_mfma_f32_16x16x32_f16(Ah, Bl, accA[nf], 0, 0, 0);
                    accA[nf] = __builtin_amdgcn_mfma_f32_16x16x32_f16(Al, Bh, accA[nf], 0, 0, 0);
                }
            }
        }

        // partial C -> LDS (summed at record time): Cred[w*16+pix16][ch(33)]
        float* Cred = (float*)arena;
#pragma unroll
        for (int nf = 0; nf < 2; ++nf)
#pragma unroll
            for (int v4 = 0; v4 < 4; ++v4)
                Cred[(w * 16 + (lhi << 2) + v4) * 33 + nf * 16 + l15] = accA[nf][v4];
    }
    __syncthreads();

    // ---------------- records: 32 pix x 9 n ----------------
    {
        const float* Cred = (const float*)arena;
#pragma unroll
        for (int j = 0; j < 2; ++j) {
            int rid = j * 256 + t;
            if (rid < 288) {
                int pb = rid & 31;
                int n = rid >> 5;
                int base0 = (((pb >> 4) * 2) * 16 + (pb & 15)) * 33;
                int base1 = base0 + 16 * 33;
                float sx = Cred[base0 + n] + Cred[base1 + n];
                float sy = Cred[base0 + 9 + n] + Cred[base1 + 9 + n];
                float sm = Cred[base0 + 18 + n] + Cred[base1 + 18 + n];

                int jj = col0 + pb;
                float px = ((sx + shift_b[n]) + (float)(n / 3 - 1)) + (float)(row + 1);
                float py = ((sy + shift_b[9 + n]) + (float)(n % 3 - 1)) + (float)(jj + 1);
                float mod = 1.f / (1.f + expf(-(sm + mod_b[n])));

                float fx = floorf(px), fy = floorf(py);
                int ltx = (int)fminf(fmaxf(fx, 0.f), 63.f);
                int lty = (int)fminf(fmaxf(fy, 0.f), 63.f);
                int rbx = (int)fminf(fmaxf(fx + 1.f, 0.f), 63.f);
                int rby = (int)fminf(fmaxf(fy + 1.f, 0.f), 63.f);
                int pxi = (int)fminf(fmaxf(px, 0.f), 63.f);
                int pyi = (int)fminf(fmaxf(py, 0.f), 63.f);

                int g_lt = (1 + ltx - pxi) * (1 + lty - pyi);
                int g_rb = (1 - rbx + pxi) * (1 - rby + pyi);
                int g_lb = (1 + ltx - pxi) * (1 + rby - pyi);
                int g_rt = (1 - rbx + pxi) * (1 - lty + pyi);

                int qxa[4] = {ltx, rbx, ltx, rbx};
                int qya[4] = {lty, rby, rby, lty};
                int gga[4] = {g_lt, g_rb, g_lb, g_rt};
                unsigned w0 = 0, w1 = 0;
#pragma unroll
                for (int jq = 0; jq < 4; ++jq) {
                    bool valid = (qxa[jq] >= 1) && (qya[jq] >= 1);
                    unsigned idx = valid ? (unsigned)((qxa[jq] - 1) * 64 + (qya[jq] - 1)) : 0u;
                    unsigned gc = valid ? (unsigned)gga[jq] : 0u;   // 0..2
                    if (jq < 2) w0 |= idx << (12 * jq); else w1 |= idx << (12 * (jq - 2));
                    w0 |= gc << (24 + 2 * jq);
                }
                recU[n][pb] = make_uint2(w0, w1);
                recF[n][pb] = mod;
            }
        }
    }
    __syncthreads();

    // ---------------- Phase B: main GEMM over 9 taps (pipelined) ----------------
    int wm = w >> 1, wn = w & 1;
    int mA = t >> 3, cg = t & 7;     // A-build task: pixel mA, c-group cg

    f32x4 acc[4];
#pragma unroll
    for (int g = 0; g < 4; ++g) acc[g] = (f32x4){0.f, 0.f, 0.f, 0.f};

    // prologue: gathers for n=0
    uint2 rcA = recU[0][mA];
    float mdA = recF[0][mA];
    uint4 gA[4];
#pragma unroll
    for (int j = 0; j < 4; ++j) {
        int id = (int)((j < 2 ? (rcA.x >> (12 * j)) : (rcA.y >> (12 * (j - 2)))) & 0xFFF);
        gA[j] = *(const uint4*)(xbh + (id << 6) + (cg << 3));
    }

#pragma unroll
    for (int n = 0; n < 9; ++n) {
        // B fragments (L1-resident W); consumed after the barrier
        const __half* Wn = WtH + n * 8192;
        uint4 Bv[2][4];
#pragma unroll
        for (int ks = 0; ks < 2; ++ks)
#pragma unroll
            for (int g = 0; g < 4; ++g)
                Bv[ks][g] = *(const uint4*)(Wn + ((wn * 64 + g * 16 + l15) << 6) +
                                            ks * 32 + (lhi << 3));

        // combine current gathers
        __align__(16) __half2 a[4];
        a[0] = __half2(0, 0); a[1] = __half2(0, 0);
        a[2] = __half2(0, 0); a[3] = __half2(0, 0);
#pragma unroll
        for (int j = 0; j < 4; ++j) {
            float wf = (float)((rcA.x >> (24 + 2 * j)) & 3) * mdA;
            __half2 wh2 = __half2(__float2half_rn(wf), __float2half_rn(wf));
            const __half2* vv = (const __half2*)&gA[j];
            a[0] = __hfma2(wh2, vv[0], a[0]);
            a[1] = __hfma2(wh2, vv[1], a[1]);
            a[2] = __hfma2(wh2, vv[2], a[2]);
            a[3] = __hfma2(wh2, vv[3], a[3]);
        }

        // prefetch next tap's gathers (latency hidden under stage+bar+MFMA)
        if (n < 8) {
            rcA = recU[n + 1][mA];
            mdA = recF[n + 1][mA];
#pragma unroll
            for (int j = 0; j < 4; ++j) {
                int id = (int)((j < 2 ? (rcA.x >> (12 * j)) : (rcA.y >> (12 * (j - 2)))) & 0xFFF);
                gA[j] = *(const uint4*)(xbh + (id << 6) + (cg << 3));
            }
        }

        // stage into slab[n&1]
        *(uint4*)&arena[((n & 1) << 12) | (mA << 7) | ((cg ^ (mA & 7)) << 4)] =
            *(uint4*)a;
        __syncthreads();   // slab[n&1] complete (double-buffer -> 1 bar/n)

        // MFMA: A rows wm*16 + l15, k = ks*32 + lhi*8
#pragma unroll
        for (int ks = 0; ks < 2; ++ks) {
            int rowa = wm * 16 + l15;
            int gr = (ks * 4 + lhi) ^ (rowa & 7);
            half8_t Af = *(const half8_t*)&arena[((n & 1) << 12) | (rowa << 7) | (gr << 4)];
#pragma unroll
            for (int g = 0; g < 4; ++g) {
                half8_t Bf = *(half8_t*)&Bv[ks][g];
                acc[g] = __builtin_amdgcn_mfma_f32_16x16x32_f16(Af, Bf, acc[g], 0, 0, 0);
            }
        }
    }

    // ---------------- Epilogue: 4 rounds of 32 o-rows ----------------
    float* Ep = (float*)(arena + 8448);   // [32 o][33 m] scalar, conflict-free
    float* ob = out + ((size_t)b << 19);
    int prow = row * 64 + col0;
#pragma unroll
    for (int r = 0; r < 4; ++r) {
        if (wn == (r >> 1)) {
#pragma unroll
            for (int gg = 0; gg < 2; ++gg) {
                int g = (r & 1) * 2 + gg;
                int o_loc = gg * 16 + l15;
#pragma unroll
                for (int v4 = 0; v4 < 4; ++v4)
                    Ep[o_loc * 33 + wm * 16 + (lhi << 2) + v4] = acc[g][v4];
            }
        }
        __syncthreads();
        {
            int o_loc = t >> 3;          // 0..31
            int mseg = t & 7;            // 0..7
            float4 fa;
            fa.x = Ep[o_loc * 33 + mseg * 4 + 0];
            fa.y = Ep[o_loc * 33 + mseg * 4 + 1];
            fa.z = Ep[o_loc * 33 + mseg * 4 + 2];
            fa.w = Ep[o_loc * 33 + mseg * 4 + 3];
            float* dst = ob + ((size_t)(r * 32 + o_loc) << 12) + prow + mseg * 4;
            *(float4*)dst = fa;
        }
        __syncthreads();
    }
}

// ---------------------------------------------------------------------------
extern "C" void kernel_launch(void* const* d_in, const int* in_sizes, int n_in,
                              void* d_out, int out_size, void* d_ws, size_t ws_size,
                              hipStream_t stream) {
    const float* x = (const float*)d_in[0];
    const float* shift_w = (const float*)d_in[1];
    const float* shift_b = (const float*)d_in[2];
    const float* mod_w = (const float*)d_in[3];
    const float* mod_b = (const float*)d_in[4];
    const float* conv_w = (const float*)d_in[5];
    float* out = (float*)d_out;

    char* ws = (char*)d_ws;
    __half* xTh = (__half*)ws;                       // 4 MB
    __half* xTl = (__half*)(ws + 4194304);           // 4 MB
    __half* WtH = (__half*)(ws + 8388608);           // 144 KB
    __half* WtSh = (__half*)(ws + 8536064);          // 36 KB
    __half* WtSl = (__half*)(ws + 8572928);          // 36 KB  (total 8.61 MB)

    k_pre<<<dim3(872), dim3(256), 0, stream>>>(x, conv_w, shift_w, mod_w,
                                               xTh, xTl, WtH, WtSh, WtSl);
    k_fused<<<dim3(1024), dim3(256), 0, stream>>>(xTh, xTl, WtH, WtSh, WtSl,
                                                  shift_b, mod_b, out);
}